// Round 6
// baseline (69.041 us; speedup 1.0000x reference)
//
#include <hip/hip_runtime.h>

// Element ids
#define E_EMPTY  0
#define E_WALL   1
#define E_SAND   2
#define E_WATER  3
#define E_GAS    4
#define E_WOOD   5
#define E_ICE    6
#define E_FIRE   7
#define E_PLANT  8
#define E_STONE  9
#define E_LAVA   10
#define E_ACID   11
#define E_DUST   12
#define E_CLONER 13

#define CH 18
#define HW (512*512)          // 2^18
#define NPIX (4*HW)
#define NWORLD (4*CH*HW)

// dens+1 packed as nibbles (e=0..13): values {1,6,4,3,0,6,6,1,6,5,4,3,4,6}
#define PACKD 0x64345616603461ULL
// gravity bitmask: bit e set iff GRAVITY[e]==1
#define GMASK 7901
// is_block (not EMPTY/WALL/ACID/CLONER)
#define BMASK 6140
// burnable (WOOD|PLANT|GAS|DUST)
#define BURNM 4400

__constant__ float c_dens[14] = {0.f,5.f,3.f,2.f,-1.f,5.f,5.f,0.f,5.f,4.f,3.f,2.f,3.f,5.f};
__constant__ float c_grav[14] = {1.f,0.f,1.f,1.f,1.f,0.f,1.f,1.f,0.f,1.f,1.f,1.f,1.f,0.f};

__device__ __forceinline__ bool is_block_e(int e) { return (BMASK >> e) & 1; }
__device__ __forceinline__ int is_burnable_e(int e) { return (BURNM >> e) & 1; }
__device__ __forceinline__ int fl01(int e) { return (e == E_FIRE || e == E_LAVA) ? 1 : 0; }

// ---- K1: decode one-hot world (9 planes) -> u8 id; fold all rand thresholds -> bit-pack.
// rb bits: 0: ri<0.05, 1: ri<0.2, 2: ri<0.3, 3: re<0.4, 4: rm>0.5, 5: dg<=0
__device__ __forceinline__ unsigned char decode1(float d, float g, float f, float wa,
                                                 float wo, float pl, float sa, float lv, float wt) {
  if (g < 0.5f) {
    if (wa > 0.5f) return E_WALL;
    if (wo > 0.5f) return E_WOOD;
    if (pl > 0.5f) return E_PLANT;
    return E_CLONER;
  }
  int di = (int)d;          // d in {-1,0,2,3,4,5}, exact
  if (di == 0) return (f > 0.5f) ? E_FIRE : E_EMPTY;
  if (di == 5) return E_ICE;
  if (di == 4) return E_STONE;
  if (di < 0)  return E_GAS;
  if (di == 3) { if (sa > 0.5f) return E_SAND; if (lv > 0.5f) return E_LAVA; return E_DUST; }
  return (wt > 0.5f) ? E_WATER : E_ACID;
}

__global__ __launch_bounds__(256) void k_prep(const float* __restrict__ w,
                                              const float* __restrict__ ri,
                                              const float* __restrict__ re,
                                              const float* __restrict__ rm,
                                              const float* __restrict__ dg,
                                              unsigned char* __restrict__ e0,
                                              unsigned char* __restrict__ rb) {
  int g = blockIdx.x * 256 + threadIdx.x;
  int base = g << 2;
  int b = base >> 18;
  int r = base & (HW - 1);
  const float* wb = w + (size_t)b * CH * HW + r;
  float4 D  = *reinterpret_cast<const float4*>(wb + (size_t)14 * HW);
  float4 G  = *reinterpret_cast<const float4*>(wb + (size_t)15 * HW);
  float4 F  = *reinterpret_cast<const float4*>(wb + (size_t)7  * HW);
  float4 WA = *reinterpret_cast<const float4*>(wb + (size_t)1  * HW);
  float4 WO = *reinterpret_cast<const float4*>(wb + (size_t)5  * HW);
  float4 PL = *reinterpret_cast<const float4*>(wb + (size_t)8  * HW);
  float4 SA = *reinterpret_cast<const float4*>(wb + (size_t)2  * HW);
  float4 LV = *reinterpret_cast<const float4*>(wb + (size_t)10 * HW);
  float4 WT = *reinterpret_cast<const float4*>(wb + (size_t)3  * HW);
  uchar4 e;
  e.x = decode1(D.x, G.x, F.x, WA.x, WO.x, PL.x, SA.x, LV.x, WT.x);
  e.y = decode1(D.y, G.y, F.y, WA.y, WO.y, PL.y, SA.y, LV.y, WT.y);
  e.z = decode1(D.z, G.z, F.z, WA.z, WO.z, PL.z, SA.z, LV.z, WT.z);
  e.w = decode1(D.w, G.w, F.w, WA.w, WO.w, PL.w, SA.w, LV.w, WT.w);
  *reinterpret_cast<uchar4*>(e0 + base) = e;

  float4 RI = *reinterpret_cast<const float4*>(ri + base);
  float4 RE = *reinterpret_cast<const float4*>(re + base);
  float4 RM = *reinterpret_cast<const float4*>(rm + base);
  float4 DG = *reinterpret_cast<const float4*>(dg + base);
  uchar4 q;
  q.x = (RI.x<0.05f?1:0)|(RI.x<0.2f?2:0)|(RI.x<0.3f?4:0)|(RE.x<0.4f?8:0)|(RM.x>0.5f?16:0)|(DG.x<=0.f?32:0);
  q.y = (RI.y<0.05f?1:0)|(RI.y<0.2f?2:0)|(RI.y<0.3f?4:0)|(RE.y<0.4f?8:0)|(RM.y>0.5f?16:0)|(DG.y<=0.f?32:0);
  q.z = (RI.z<0.05f?1:0)|(RI.z<0.2f?2:0)|(RI.z<0.3f?4:0)|(RE.z<0.4f?8:0)|(RM.z>0.5f?16:0)|(DG.z<=0.f?32:0);
  q.w = (RI.w<0.05f?1:0)|(RI.w<0.2f?2:0)|(RI.w<0.3f?4:0)|(RE.w<0.4f?8:0)|(RM.w>0.5f?16:0)|(DG.w<=0.f?32:0);
  *reinterpret_cast<uchar4*>(rb + base) = q;
}

// ============ K2: fused stencil chain + fluid + cloner, OUT=2 bands, separable convs ======
// LDS arena rows (each 512B), lifetimes:
//   RB  [0,14)  rb, whole kernel              (abs row = ty + idx - 6)
//   A   [14,28) e0(14) -> Hf(12) -> Hb(10) -> G(8)
//   EAS [28,40) eas(12) -> Hg(8)              (abs = ty + idx - 5)
//   B1  [40,50) b1(10)                        (abs = ty + idx - 4)
//   HBN [50,58) hbn(8)                        (abs = ty + idx - 3)
//   EF  [58,64) eF(6)                         (abs = ty + idx - 2)
//   EL  [64,70) eL(6)                         (abs = ty + idx - 2)
#define R_RB  0
#define R_A   14
#define R_EAS 28
#define R_B1  40
#define R_HBN 50
#define R_EF  58
#define R_EL  64

// fluid macros (named scalars only; P = dens-nibble | grav<<4 carried through swaps)
#define PROPS(E) ((int)((PACKD >> ((E)*4)) & 15) | ((((GMASK) >> (E)) & 1) << 4))
#define FD(M,BIT) (((M) > 0 || ((M) == 0 && ((rmb >> (BIT)) & 1))) ? 1 : 0)

#define STEPL(NE_,NP_,EC,PC,EW,PW,EE,PE,FC,FE,NDC,NDE,MOM) { \
  bool dbl = (FC) && ((EC)==el) && (NDC) && (((PC)&15) > ((PW)&15)) && ((PW)&16) && ((PC)&16); \
  bool dbr = (FE) && ((EE)==el) && (NDE) && (((PE)&15) > ((PC)&15)) && ((PE)&16) && ((PC)&16); \
  MOM += dbr ? 2 : 0; \
  NE_ = dbl ? (EW) : (dbr ? (EE) : (EC)); \
  NP_ = dbl ? (PW) : (dbr ? (PE) : (PC)); }

#define STEPR(NE_,NP_,EC,PC,EW,PW,EE,PE,FC,FW,NDC,NDW,MOM) { \
  bool dbl = !(FC) && ((EC)==el) && (NDC) && (((PC)&15) > ((PE)&15)) && ((PE)&16) && ((PC)&16); \
  bool dbr = !(FW) && ((EW)==el) && (NDW) && (((PW)&15) > ((PC)&15)) && ((PW)&16) && ((PC)&16); \
  MOM -= dbr ? 2 : 0; \
  NE_ = dbl ? (EE) : (dbr ? (EW) : (EC)); \
  NP_ = dbl ? (PE) : (dbr ? (PW) : (PC)); }

#define FDEF int f0=FD(M0,0), f1=FD(M1,1), f2=FD(M2,2), f3=FD(M3,3), \
                 f4=FD(M4,4), f5=FD(M5,5), f6=FD(M6,6), f7=FD(M7,7)

__global__ __launch_bounds__(512) void k_rest(const unsigned char* __restrict__ e0g,
                                              const unsigned char* __restrict__ rbg,
                                              const float* __restrict__ vin,
                                              float* __restrict__ out) {
  __shared__ unsigned char S[70][512];
  __shared__ signed char nms[2][512];

  int tid = threadIdx.x;
  int blk = blockIdx.x;
  int b = blk >> 8;                 // 256 bands per batch
  int ty = (blk & 255) << 1;        // OUT = 2
  int bbase = b * HW;
  float* vout = out + NWORLD;
  int x = tid;

  // ---- stage e0 + rb rows [ty-6, ty+8) (14 rows), uchar4
  for (int q = tid; q < 14*128; q += 512) {
    int l = q >> 7, c4 = (q & 127) << 2;
    int gy = (ty + l - 6) & 511;
    int gi = bbase + (gy << 9) + c4;
    *reinterpret_cast<uchar4*>(&S[R_A + l][c4]) = *reinterpret_cast<const uchar4*>(e0g + gi);
    *reinterpret_cast<uchar4*>(&S[R_RB + l][c4]) = *reinterpret_cast<const uchar4*>(rbg + gi);
  }
  __syncthreads();

  // ---- acid -> EAS[0..11] (abs ty+l-5), vertical roll (wrapped staging)
  #pragma unroll
  for (int l = 0; l < 12; ++l) {
    int ec = S[R_A+l+1][x], eu = S[R_A+l][x], ed = S[R_A+l+2][x];
    bool arc = (S[R_RB+l+1][x] & 2) != 0;
    bool aru = (S[R_RB+l][x]   & 2) != 0;
    bool ard = (S[R_RB+l+2][x] & 2) != 0;
    bool does_acid  = (ec == E_ACID) && arc && (is_block_e(ed) || is_block_e(eu));
    bool does_block = is_block_e(ec) && ((aru && eu == E_ACID) || (ard && ed == E_ACID));
    S[R_EAS+l][x] = (does_acid || does_block) ? (unsigned char)E_EMPTY : (unsigned char)ec;
  }
  __syncthreads();

  // ---- Hf[0..11] = horizontal OR of fire|lava(EAS), zero-pad at x edges (overwrites e0)
  #pragma unroll
  for (int l = 0; l < 12; ++l) {
    int c = fl01(S[R_EAS+l][x]);
    int a = (x == 0)   ? 0 : fl01(S[R_EAS+l][x-1]);
    int d = (x == 511) ? 0 : fl01(S[R_EAS+l][x+1]);
    S[R_A+l][x] = (unsigned char)(a | c | d);
  }
  __syncthreads();

  // ---- fire1 -> B1[0..9] (abs ty+l-4): hfn = vertical OR of Hf with zero-pad rows
  #pragma unroll
  for (int l = 0; l < 10; ++l) {
    int gy = ty + l - 4;  // may be <0 or >511 only via wrap; mask uses true abs row
    int ga = (gy + 512) & 511;
    int hf = S[R_A+l+1][x];
    hf |= (ga == 0)   ? 0 : S[R_A+l][x];
    hf |= (ga == 511) ? 0 : S[R_A+l+2][x];
    bool hfn = hf != 0;
    int ec = S[R_EAS+l+1][x];
    int rbv = S[R_RB+l+2][x];
    bool db = (ec==E_WOOD && (rbv&1)) || (ec==E_PLANT && (rbv&2)) ||
              (ec==E_GAS  && (rbv&2)) || (ec==E_DUST);
    bool does_burn = db && hfn;
    bool db_ice = (ec==E_ICE) && (rbv&2) && hfn;
    int e1 = does_burn ? E_FIRE : (db_ice ? E_WATER : ec);
    S[R_B1+l][x] = (unsigned char)(e1 | (does_burn?16:0) | ((ec==E_DUST && hfn)?32:0));
  }
  __syncthreads();

  // ---- Hb[0..9] = horizontal sum of burnable(e1) (overwrites Hf)
  #pragma unroll
  for (int l = 0; l < 10; ++l) {
    int c = is_burnable_e(S[R_B1+l][x] & 15);
    int a = (x == 0)   ? 0 : is_burnable_e(S[R_B1+l][x-1] & 15);
    int d = (x == 511) ? 0 : is_burnable_e(S[R_B1+l][x+1] & 15);
    S[R_A+l][x] = (unsigned char)(a + c + d);
  }
  __syncthreads();

  // ---- hbn -> HBN[0..7] (abs ty+l-3): vertical sum of Hb with row masks
  #pragma unroll
  for (int l = 0; l < 8; ++l) {
    int ga = (ty + l - 3 + 512) & 511;
    int s = S[R_A+l+1][x];
    s += (ga == 0)   ? 0 : S[R_A+l][x];
    s += (ga == 511) ? 0 : S[R_A+l+2][x];
    S[R_HBN+l][x] = (unsigned char)s;
  }
  __syncthreads();

  // ---- G[0..7] (abs ty+l-3) = hbn * fl01(eA) + lava01(e1) (overwrites Hb)
  #pragma unroll
  for (int l = 0; l < 8; ++l) {
    int g = (int)S[R_HBN+l][x] * fl01(S[R_EAS+l+2][x])
          + (((S[R_B1+l+1][x] & 15) == E_LAVA) ? 1 : 0);
    S[R_A+l][x] = (unsigned char)g;
  }
  __syncthreads();

  // ---- Hg[0..7] = horizontal sum of G (overwrites EAS)
  #pragma unroll
  for (int l = 0; l < 8; ++l) {
    int c = S[R_A+l][x];
    int a = (x == 0)   ? 0 : S[R_A+l][x-1];
    int d = (x == 511) ? 0 : S[R_A+l][x+1];
    S[R_EAS+l][x] = (unsigned char)(a + c + d);
  }
  __syncthreads();

  // ---- fire2 -> EF[0..5] (abs ty+l-2); velocity for rows [0,2)
  #pragma unroll
  for (int l = 0; l < 6; ++l) {
    int ga = (ty + l - 2 + 512) & 511;
    int ifr = S[R_EAS+l+1][x];
    ifr += (ga == 0)   ? 0 : S[R_EAS+l][x];
    ifr += (ga == 511) ? 0 : S[R_EAS+l+2][x];
    int e1 = S[R_B1+l+2][x] & 15;
    int rbv = S[R_RB+l+4][x];
    bool db_empty = (e1 == E_EMPTY) && (ifr > 0) && ((rbv & 4) != 0);
    int e2 = db_empty ? E_FIRE : e1;
    bool fire_empty = (e2 == E_FIRE) && ((rbv & 8) != 0) && (S[R_HBN+l+1][x] == 0);
    S[R_EF+l][x] = fire_empty ? (unsigned char)E_EMPTY : (unsigned char)e2;
  }
  {
    int xl1 = (x + 511) & 511, xr1 = (x + 1) & 511;
    #pragma unroll
    for (int r = 0; r < 2; ++r) {
      int gy = ty + r;
      int fu  = S[R_B1+r+3][x];
      int fd_ = S[R_B1+r+5][x];
      int flf = S[R_B1+r+4][xl1];
      int frt = S[R_B1+r+4][xr1];
      float vy = vin[(size_t)(b*2+0)*HW + (gy<<9) + x];
      vy = vy + 2.0f*(float)((fu>>4)&1);   vy = vy - 2.0f*(float)((fd_>>4)&1);
      vy = vy + 20.0f*(float)((fu>>5)&1);  vy = vy - 20.0f*(float)((fd_>>5)&1);
      float vx = vin[(size_t)(b*2+1)*HW + (gy<<9) + x];
      vx = vx + 2.0f*(float)((flf>>4)&1);  vx = vx - 2.0f*(float)((frt>>4)&1);
      vx = vx + 20.0f*(float)((flf>>5)&1); vx = vx - 20.0f*(float)((frt>>5)&1);
      vout[(size_t)(b*2+0)*HW + (gy<<9) + x] = vy;
      vout[(size_t)(b*2+1)*HW + (gy<<9) + x] = vx;
    }
  }
  __syncthreads();

  // ---- fluid: waves 0..5 each own EF row w (abs ty+w-2); registers + edge shuffles
  {
    int w = tid >> 6, lane = tid & 63;
    if (w < 6) {
      uint2 ev = *reinterpret_cast<const uint2*>(&S[R_EF+w][lane << 3]);
      int E0 =  ev.x        & 255, E1 = (ev.x >> 8) & 255,
          E2 = (ev.x >> 16) & 255, E3 = (ev.x >> 24) & 255,
          E4 =  ev.y        & 255, E5 = (ev.y >> 8) & 255,
          E6 = (ev.y >> 16) & 255, E7 = (ev.y >> 24) & 255;
      uint2 qv = *reinterpret_cast<const uint2*>(&S[R_RB+w+4][lane << 3]);
      int rmb = ((qv.x>>4)&1) | (((qv.x>>12)&1)<<1) | (((qv.x>>20)&1)<<2) | (((qv.x>>28)&1)<<3)
              | (((qv.y>>4)&1)<<4) | (((qv.y>>12)&1)<<5) | (((qv.y>>20)&1)<<6) | (((qv.y>>28)&1)<<7);
      int nd0 = (qv.x>>5)&1,  nd1 = (qv.x>>13)&1, nd2 = (qv.x>>21)&1, nd3 = (qv.x>>29)&1,
          nd4 = (qv.y>>5)&1,  nd5 = (qv.y>>13)&1, nd6 = (qv.y>>21)&1, nd7 = (qv.y>>29)&1;
      int P0=PROPS(E0), P1=PROPS(E1), P2=PROPS(E2), P3=PROPS(E3),
          P4=PROPS(E4), P5=PROPS(E5), P6=PROPS(E6), P7=PROPS(E7);
      int M0=0,M1=0,M2=0,M3=0,M4=0,M5=0,M6=0,M7=0;

      int laneL = (lane + 63) & 63, laneR = (lane + 1) & 63;
      int ndpk = nd0 | (nd7 << 1);
      int ndl = (__shfl(ndpk, laneL, 64) >> 1) & 1;
      int ndr =  __shfl(ndpk, laneR, 64) & 1;

      #pragma unroll
      for (int ei = 0; ei < 5; ++ei) {
        const int el = (ei==0) ? E_EMPTY : (ei==1) ? E_WATER : (ei==2) ? E_GAS
                     : (ei==3) ? E_LAVA  : E_ACID;
        { // fall_left
          FDEF;
          int pl_ = __shfl(E7 | (f7 << 8) | (P7 << 9), laneL, 64);
          int pr_ = __shfl(E0 | (f0 << 8) | (P0 << 9), laneR, 64);
          int EBL = pl_ & 255, PBL = (pl_ >> 9) & 31;
          int EBR = pr_ & 255, FBR = (pr_ >> 8) & 1, PBR = (pr_ >> 9) & 31;
          int N0,N1,N2,N3,N4,N5,N6,N7, Q0,Q1,Q2,Q3,Q4,Q5,Q6,Q7;
          STEPL(N0,Q0,E0,P0,EBL,PBL,E1,P1,f0,f1, nd0,nd1,M0);
          STEPL(N1,Q1,E1,P1,E0, P0, E2,P2,f1,f2, nd1,nd2,M1);
          STEPL(N2,Q2,E2,P2,E1, P1, E3,P3,f2,f3, nd2,nd3,M2);
          STEPL(N3,Q3,E3,P3,E2, P2, E4,P4,f3,f4, nd3,nd4,M3);
          STEPL(N4,Q4,E4,P4,E3, P3, E5,P5,f4,f5, nd4,nd5,M4);
          STEPL(N5,Q5,E5,P5,E4, P4, E6,P6,f5,f6, nd5,nd6,M5);
          STEPL(N6,Q6,E6,P6,E5, P5, E7,P7,f6,f7, nd6,nd7,M6);
          STEPL(N7,Q7,E7,P7,E6, P6,EBR,PBR,f7,FBR,nd7,ndr,M7);
          E0=N0;E1=N1;E2=N2;E3=N3;E4=N4;E5=N5;E6=N6;E7=N7;
          P0=Q0;P1=Q1;P2=Q2;P3=Q3;P4=Q4;P5=Q5;P6=Q6;P7=Q7;
        }
        { // fall_right
          FDEF;
          int pl_ = __shfl(E7 | (f7 << 8) | (P7 << 9), laneL, 64);
          int pr_ = __shfl(E0 | (f0 << 8) | (P0 << 9), laneR, 64);
          int EBL = pl_ & 255, FBL = (pl_ >> 8) & 1, PBL = (pl_ >> 9) & 31;
          int EBR = pr_ & 255, PBR = (pr_ >> 9) & 31;
          int N0,N1,N2,N3,N4,N5,N6,N7, Q0,Q1,Q2,Q3,Q4,Q5,Q6,Q7;
          STEPR(N0,Q0,E0,P0,EBL,PBL,E1,P1,f0,FBL,nd0,ndl,M0);
          STEPR(N1,Q1,E1,P1,E0, P0, E2,P2,f1,f0, nd1,nd0,M1);
          STEPR(N2,Q2,E2,P2,E1, P1, E3,P3,f2,f1, nd2,nd1,M2);
          STEPR(N3,Q3,E3,P3,E2, P2, E4,P4,f3,f2, nd3,nd2,M3);
          STEPR(N4,Q4,E4,P4,E3, P3, E5,P5,f4,f3, nd4,nd3,M4);
          STEPR(N5,Q5,E5,P5,E4, P4, E6,P6,f5,f4, nd5,nd4,M5);
          STEPR(N6,Q6,E6,P6,E5, P5, E7,P7,f6,f5, nd6,nd5,M6);
          STEPR(N7,Q7,E7,P7,E6, P6,EBR,PBR,f7,f6, nd7,nd6,M7);
          E0=N0;E1=N1;E2=N2;E3=N3;E4=N4;E5=N5;E6=N6;E7=N7;
          P0=Q0;P1=Q1;P2=Q2;P3=Q3;P4=Q4;P5=Q5;P6=Q6;P7=Q7;
        }
      }
      unsigned int w0 = (unsigned)E0 | ((unsigned)E1<<8) | ((unsigned)E2<<16) | ((unsigned)E3<<24);
      unsigned int w1 = (unsigned)E4 | ((unsigned)E5<<8) | ((unsigned)E6<<16) | ((unsigned)E7<<24);
      *reinterpret_cast<uint2*>(&S[R_EL+w][lane << 3]) = make_uint2(w0, w1);
      if (w == 2 || w == 3) {
        unsigned int m0 = (M0&255) | ((M1&255)<<8) | ((M2&255)<<16) | ((unsigned)(M3&255)<<24);
        unsigned int m1 = (M4&255) | ((M5&255)<<8) | ((M6&255)<<16) | ((unsigned)(M7&255)<<24);
        *reinterpret_cast<uint2*>(reinterpret_cast<unsigned char*>(&nms[w-2][0]) + (lane << 3)) =
            make_uint2(m0, m1);
      }
    }
  }
  __syncthreads();

  // ---- cloner + expand to 18-ch output: 256 threads, quad (row r=tid>>7, x0=(tid&127)*4)
  if (tid < 256) {
    int r = tid >> 7;               // 0..1
    int x0 = (tid & 127) << 2;
    const int DY[4] = {1, -1, 0, 0};
    const int DX[4] = {0, 0, -1, 1};
    int eo[4]; float mom[4], cao[4];
    #pragma unroll
    for (int k = 0; k < 4; ++k) {
      int xx = x0 + k;
      int ry = r + 2;               // EL row of this cell
      int ec = S[R_EL+ry][xx];
      float m = (float)nms[r][xx];
      int e = ec; float ca = 0.f;
      if (ec == E_CLONER) {
        int c = S[R_EL+ry+1][xx];
        if (c==0||c==13) c = S[R_EL+ry-1][xx];
        if (c==0||c==13) c = S[R_EL+ry][(xx+511)&511];
        if (c==0||c==13) c = S[R_EL+ry][(xx+1)&511];
        ca = (float)c;
      } else if (ec == E_EMPTY) {
        #pragma unroll
        for (int d = 0; d < 4; ++d) {
          int qy = ry + DY[d], qx = (xx + DX[d]) & 511;
          if (S[R_EL+qy][qx] == E_CLONER) {
            int c = S[R_EL+qy+1][qx];
            if (c==0||c==13) c = S[R_EL+qy-1][qx];
            if (c==0||c==13) c = S[R_EL+qy][(qx+511)&511];
            if (c==0||c==13) c = S[R_EL+qy][(qx+1)&511];
            if (c != 0 && c != 13) { e = c; m = 0.f; break; }
          }
        }
      }
      eo[k] = e; mom[k] = m; cao[k] = ca;
    }
    float* ob = out + (size_t)b * CH * HW + ((ty + r) << 9) + x0;
    #pragma unroll
    for (int c = 0; c < 14; ++c) {
      float4 v = make_float4(eo[0]==c ? 1.f : 0.f, eo[1]==c ? 1.f : 0.f,
                             eo[2]==c ? 1.f : 0.f, eo[3]==c ? 1.f : 0.f);
      *reinterpret_cast<float4*>(ob + (size_t)c * HW) = v;
    }
    *reinterpret_cast<float4*>(ob + (size_t)14*HW) =
        make_float4(c_dens[eo[0]], c_dens[eo[1]], c_dens[eo[2]], c_dens[eo[3]]);
    *reinterpret_cast<float4*>(ob + (size_t)15*HW) =
        make_float4(c_grav[eo[0]], c_grav[eo[1]], c_grav[eo[2]], c_grav[eo[3]]);
    *reinterpret_cast<float4*>(ob + (size_t)16*HW) =
        make_float4(mom[0], mom[1], mom[2], mom[3]);
    *reinterpret_cast<float4*>(ob + (size_t)17*HW) =
        make_float4(cao[0], cao[1], cao[2], cao[3]);
  }
}

extern "C" void kernel_launch(void* const* d_in, const int* in_sizes, int n_in,
                              void* d_out, int out_size, void* d_ws, size_t ws_size,
                              hipStream_t stream) {
  const float* world = (const float*)d_in[0];
  const float* rm    = (const float*)d_in[1];
  const float* ri    = (const float*)d_in[2];
  const float* re    = (const float*)d_in[3];
  const float* vel   = (const float*)d_in[4];
  const float* dg    = (const float*)d_in[5];
  float* out = (float*)d_out;

  char* ws = (char*)d_ws;
  unsigned char* e0 = (unsigned char*)ws;
  unsigned char* rb = e0 + NPIX;

  hipLaunchKernelGGL(k_prep, dim3(NPIX/1024), dim3(256), 0, stream,
                     world, ri, re, rm, dg, e0, rb);
  hipLaunchKernelGGL(k_rest, dim3(4*256), dim3(512), 0, stream,
                     e0, rb, vel, out);
}

// Round 7
// 46.575 us; speedup vs baseline: 1.4824x; 1.4824x over previous
//
#include <hip/hip_runtime.h>

// Element ids
#define E_EMPTY  0
#define E_WALL   1
#define E_SAND   2
#define E_WATER  3
#define E_GAS    4
#define E_WOOD   5
#define E_ICE    6
#define E_FIRE   7
#define E_PLANT  8
#define E_STONE  9
#define E_LAVA   10
#define E_ACID   11
#define E_DUST   12
#define E_CLONER 13

#define CH 18
#define HW (512*512)          // 2^18
#define NPIX (4*HW)
#define NWORLD (4*CH*HW)

// dens+1 packed as nibbles (e=0..13): values {1,6,4,3,0,6,6,1,6,5,4,3,4,6}
#define PACKD 0x64345616603461ULL
// gravity bitmask: bit e set iff GRAVITY[e]==1
#define GMASK 7901

typedef unsigned long long u64;
#define ONE8 0x0101010101010101ULL
#define K7F  0x7F7F7F7F7F7F7F7FULL
#define LOWN 0x0F0F0F0F0F0F0F0FULL

__constant__ float c_dens[14] = {0.f,5.f,3.f,2.f,-1.f,5.f,5.f,0.f,5.f,4.f,3.f,2.f,3.f,5.f};
__constant__ float c_grav[14] = {1.f,0.f,1.f,1.f,1.f,0.f,1.f,1.f,0.f,1.f,1.f,1.f,1.f,0.f};

__device__ __forceinline__ u64 bcast(int k) { return ONE8 * (unsigned)k; }
// per-byte equality -> 0x01 bytes. Requires all bytes of x and k <= 0x7F (holds everywhere here).
__device__ __forceinline__ u64 eqb(u64 x, int k) {
  u64 y = x ^ bcast(k);
  return ((~(y + K7F)) >> 7) & ONE8;
}
// 0/1-byte mask -> 0x00/0xFF byte mask
__device__ __forceinline__ u64 mexp(u64 m) { return (m << 8) - m; }
__device__ __forceinline__ u64 fl01w(u64 e) { return eqb(e, E_FIRE) | eqb(e, E_LAVA); }
__device__ __forceinline__ u64 burn01w(u64 b) {
  u64 e = b & LOWN;
  return eqb(e,E_WOOD) | eqb(e,E_PLANT) | eqb(e,E_GAS) | eqb(e,E_DUST);
}
__device__ __forceinline__ u64 isblkw(u64 e) {
  return ONE8 ^ (eqb(e,E_EMPTY) | eqb(e,E_WALL) | eqb(e,E_ACID) | eqb(e,E_CLONER));
}

// ---- K1: decode one-hot world (9 planes) -> u8 id; fold all rand thresholds -> bit-pack.
// rb bits: 0: ri<0.05, 1: ri<0.2, 2: ri<0.3, 3: re<0.4, 4: rm>0.5, 5: dg<=0
__device__ __forceinline__ unsigned char decode1(float d, float g, float f, float wa,
                                                 float wo, float pl, float sa, float lv, float wt) {
  if (g < 0.5f) {
    if (wa > 0.5f) return E_WALL;
    if (wo > 0.5f) return E_WOOD;
    if (pl > 0.5f) return E_PLANT;
    return E_CLONER;
  }
  int di = (int)d;          // d in {-1,0,2,3,4,5}, exact
  if (di == 0) return (f > 0.5f) ? E_FIRE : E_EMPTY;
  if (di == 5) return E_ICE;
  if (di == 4) return E_STONE;
  if (di < 0)  return E_GAS;
  if (di == 3) { if (sa > 0.5f) return E_SAND; if (lv > 0.5f) return E_LAVA; return E_DUST; }
  return (wt > 0.5f) ? E_WATER : E_ACID;
}

__global__ __launch_bounds__(256) void k_prep(const float* __restrict__ w,
                                              const float* __restrict__ ri,
                                              const float* __restrict__ re,
                                              const float* __restrict__ rm,
                                              const float* __restrict__ dg,
                                              unsigned char* __restrict__ e0,
                                              unsigned char* __restrict__ rb) {
  int g = blockIdx.x * 256 + threadIdx.x;
  int base = g << 2;
  int b = base >> 18;
  int r = base & (HW - 1);
  const float* wb = w + (size_t)b * CH * HW + r;
  float4 D  = *reinterpret_cast<const float4*>(wb + (size_t)14 * HW);
  float4 G  = *reinterpret_cast<const float4*>(wb + (size_t)15 * HW);
  float4 F  = *reinterpret_cast<const float4*>(wb + (size_t)7  * HW);
  float4 WA = *reinterpret_cast<const float4*>(wb + (size_t)1  * HW);
  float4 WO = *reinterpret_cast<const float4*>(wb + (size_t)5  * HW);
  float4 PL = *reinterpret_cast<const float4*>(wb + (size_t)8  * HW);
  float4 SA = *reinterpret_cast<const float4*>(wb + (size_t)2  * HW);
  float4 LV = *reinterpret_cast<const float4*>(wb + (size_t)10 * HW);
  float4 WT = *reinterpret_cast<const float4*>(wb + (size_t)3  * HW);
  uchar4 e;
  e.x = decode1(D.x, G.x, F.x, WA.x, WO.x, PL.x, SA.x, LV.x, WT.x);
  e.y = decode1(D.y, G.y, F.y, WA.y, WO.y, PL.y, SA.y, LV.y, WT.y);
  e.z = decode1(D.z, G.z, F.z, WA.z, WO.z, PL.z, SA.z, LV.z, WT.z);
  e.w = decode1(D.w, G.w, F.w, WA.w, WO.w, PL.w, SA.w, LV.w, WT.w);
  *reinterpret_cast<uchar4*>(e0 + base) = e;

  float4 RI = *reinterpret_cast<const float4*>(ri + base);
  float4 RE = *reinterpret_cast<const float4*>(re + base);
  float4 RM = *reinterpret_cast<const float4*>(rm + base);
  float4 DG = *reinterpret_cast<const float4*>(dg + base);
  uchar4 q;
  q.x = (RI.x<0.05f?1:0)|(RI.x<0.2f?2:0)|(RI.x<0.3f?4:0)|(RE.x<0.4f?8:0)|(RM.x>0.5f?16:0)|(DG.x<=0.f?32:0);
  q.y = (RI.y<0.05f?1:0)|(RI.y<0.2f?2:0)|(RI.y<0.3f?4:0)|(RE.y<0.4f?8:0)|(RM.y>0.5f?16:0)|(DG.y<=0.f?32:0);
  q.z = (RI.z<0.05f?1:0)|(RI.z<0.2f?2:0)|(RI.z<0.3f?4:0)|(RE.z<0.4f?8:0)|(RM.z>0.5f?16:0)|(DG.z<=0.f?32:0);
  q.w = (RI.w<0.05f?1:0)|(RI.w<0.2f?2:0)|(RI.w<0.3f?4:0)|(RE.w<0.4f?8:0)|(RM.w>0.5f?16:0)|(DG.w<=0.f?32:0);
  *reinterpret_cast<uchar4*>(rb + base) = q;
}

// ============ K2: SWAR stencil chain + fluid + cloner, OUT=4, u64 words (8 cells) ============
// Row arrays (u64[rows][64]), abs row = ty + idx - off:
//   RBs 16 off6 | As 16 off6: e0 -> Hf(14,off5) -> Hb(12,off4) -> G(10,off3)
//   EASs 14 off5: eas -> Hg(10,off3) | B1s 12 off4 | HBNs 10 off3 | EFs 8 off2 | ELs 8 off2

// fluid macros (named scalars only; P = dens-nibble | grav<<4 carried through swaps)
#define PROPS(E) ((int)((PACKD >> ((E)*4)) & 15) | ((((GMASK) >> (E)) & 1) << 4))
#define FD(M,BIT) (((M) > 0 || ((M) == 0 && ((rmb >> (BIT)) & 1))) ? 1 : 0)

#define STEPL(NE_,NP_,EC,PC,EW,PW,EE,PE,FC,FE,NDC,NDE,MOM) { \
  bool dbl = (FC) && ((EC)==el) && (NDC) && (((PC)&15) > ((PW)&15)) && ((PW)&16) && ((PC)&16); \
  bool dbr = (FE) && ((EE)==el) && (NDE) && (((PE)&15) > ((PC)&15)) && ((PE)&16) && ((PC)&16); \
  MOM += dbr ? 2 : 0; \
  NE_ = dbl ? (EW) : (dbr ? (EE) : (EC)); \
  NP_ = dbl ? (PW) : (dbr ? (PE) : (PC)); }

#define STEPR(NE_,NP_,EC,PC,EW,PW,EE,PE,FC,FW,NDC,NDW,MOM) { \
  bool dbl = !(FC) && ((EC)==el) && (NDC) && (((PC)&15) > ((PE)&15)) && ((PE)&16) && ((PC)&16); \
  bool dbr = !(FW) && ((EW)==el) && (NDW) && (((PW)&15) > ((PC)&15)) && ((PW)&16) && ((PC)&16); \
  MOM -= dbr ? 2 : 0; \
  NE_ = dbl ? (EE) : (dbr ? (EW) : (EC)); \
  NP_ = dbl ? (PE) : (dbr ? (PW) : (PC)); }

#define FDEF int f0=FD(M0,0), f1=FD(M1,1), f2=FD(M2,2), f3=FD(M3,3), \
                 f4=FD(M4,4), f5=FD(M5,5), f6=FD(M6,6), f7=FD(M7,7)

__global__ __launch_bounds__(512) void k_rest(const unsigned char* __restrict__ e0g,
                                              const unsigned char* __restrict__ rbg,
                                              const float* __restrict__ vin,
                                              float* __restrict__ out) {
  __shared__ u64 RBs[16][64];
  __shared__ u64 As[16][64];
  __shared__ u64 EASs[14][64];
  __shared__ u64 B1s[12][64];
  __shared__ u64 HBNs[10][64];
  __shared__ u64 EFs[8][64];
  __shared__ u64 ELs[8][64];
  __shared__ signed char nms[4][512];

  int tid = threadIdx.x;
  int blk = blockIdx.x;
  int b = blk >> 7;                 // 128 bands per batch
  int ty = (blk & 127) << 2;        // OUT = 4
  int bbase = b * HW;
  float* vout = out + NWORLD;

  // ---- stage e0 + rb rows [ty-6, ty+10): 512 threads = 16 rows x 32 chunks x 16B
  {
    int l = tid >> 5, ch = (tid & 31) << 4;
    int gy = (ty + l - 6) & 511;
    int gi = bbase + (gy << 9) + ch;
    *reinterpret_cast<uint4*>(reinterpret_cast<char*>(&As[l][0]) + ch) =
        *reinterpret_cast<const uint4*>(e0g + gi);
    *reinterpret_cast<uint4*>(reinterpret_cast<char*>(&RBs[l][0]) + ch) =
        *reinterpret_cast<const uint4*>(rbg + gi);
  }
  __syncthreads();

  int w = tid & 63, rsl = tid >> 6;

  // ---- acid -> EAS[0..13] (vertical roll, wrapped staging)
  #pragma unroll
  for (int l = rsl; l < 14; l += 8) {
    u64 eu = As[l][w], ec = As[l+1][w], ed = As[l+2][w];
    u64 ru = RBs[l][w], rc = RBs[l+1][w], rd = RBs[l+2][w];
    u64 ibu = isblkw(eu), ibc = isblkw(ec), ibd = isblkw(ed);
    u64 da = eqb(ec,E_ACID) & ((rc>>1)&ONE8) & (ibd | ibu);
    u64 db = ibc & ((((ru>>1)&ONE8) & eqb(eu,E_ACID)) | (((rd>>1)&ONE8) & eqb(ed,E_ACID)));
    EASs[l][w] = ec & ~mexp(da | db);
  }
  __syncthreads();

  // ---- Hf[0..13] -> As: horizontal OR of fire|lava(EAS); word edges = zero-pad
  #pragma unroll
  for (int l = rsl; l < 14; l += 8) {
    u64 C = fl01w(EASs[l][w]);
    u64 Lf = w ? fl01w(EASs[l][w-1]) : 0;
    u64 Rf = (w < 63) ? fl01w(EASs[l][w+1]) : 0;
    As[l][w] = C | (C<<8) | (Lf>>56) | (C>>8) | (Rf<<56);
  }
  __syncthreads();

  // ---- fire1 -> B1[0..11]: hfn = vertical OR of Hf with row zero-pad
  #pragma unroll
  for (int l = rsl; l < 12; l += 8) {
    int a = (ty + l - 4) & 511;
    u64 hf = As[l+1][w];
    if (a != 0)   hf |= As[l][w];
    if (a != 511) hf |= As[l+2][w];
    u64 e = EASs[l+1][w], rb = RBs[l+2][w];
    u64 m0 = rb & ONE8, m1 = (rb>>1) & ONE8;
    u64 eqd = eqb(e,E_DUST);
    u64 dbv = (eqb(e,E_WOOD)&m0) | (eqb(e,E_PLANT)&m1) | (eqb(e,E_GAS)&m1) | eqd;
    u64 burn = dbv & hf;
    u64 ice = eqb(e,E_ICE) & m1 & hf;
    u64 Mb = mexp(burn), Mi = mexp(ice) & ~Mb;
    u64 e1 = (bcast(E_FIRE) & Mb) | (bcast(E_WATER) & Mi) | (e & ~(Mb|Mi));
    B1s[l][w] = e1 | (burn<<4) | ((eqd & hf)<<5);
  }
  __syncthreads();

  // ---- Hb[0..11] -> As: horizontal byte-sum of burnable(e1) (max 3, carry-free)
  #pragma unroll
  for (int l = rsl; l < 12; l += 8) {
    u64 C = burn01w(B1s[l][w]);
    u64 Lb = w ? burn01w(B1s[l][w-1]) : 0;
    u64 Rb = (w < 63) ? burn01w(B1s[l][w+1]) : 0;
    As[l][w] = C + ((C<<8)|(Lb>>56)) + ((C>>8)|(Rb<<56));
  }
  __syncthreads();

  // ---- hbn -> HBN[0..9]: vertical byte-sum (max 9)
  #pragma unroll
  for (int l = rsl; l < 10; l += 8) {
    int a = (ty + l - 3) & 511;
    u64 s = As[l+1][w];
    if (a != 0)   s += As[l][w];
    if (a != 511) s += As[l+2][w];
    HBNs[l][w] = s;
  }
  __syncthreads();

  // ---- G[0..9] -> As: hbn * fl01(eA) + lava01(e1)  (max 10)
  #pragma unroll
  for (int l = rsl; l < 10; l += 8) {
    As[l][w] = (HBNs[l][w] & mexp(fl01w(EASs[l+2][w]))) + eqb(B1s[l+1][w] & LOWN, E_LAVA);
  }
  __syncthreads();

  // ---- Hg[0..9] -> EAS arena: horizontal byte-sum of G (max 30)
  #pragma unroll
  for (int l = rsl; l < 10; l += 8) {
    u64 C = As[l][w];
    u64 Lg = w ? As[l][w-1] : 0;
    u64 Rg = (w < 63) ? As[l][w+1] : 0;
    EASs[l][w] = C + ((C<<8)|(Lg>>56)) + ((C>>8)|(Rg<<56));
  }
  __syncthreads();

  // ---- fire2 -> EF[0..7] (one row per row-slot); then velocity rows [0,4)
  {
    int l = rsl;
    int a = (ty + l - 2) & 511;
    u64 ifr = EASs[l+1][w];
    if (a != 0)   ifr += EASs[l][w];
    if (a != 511) ifr += EASs[l+2][w];
    u64 nz = ((ifr + K7F) >> 7) & ONE8;        // byte > 0 (max 90+127 < 256)
    u64 e1 = B1s[l+2][w] & LOWN;
    u64 rb = RBs[l+4][w];
    u64 dbe = eqb(e1,E_EMPTY) & nz & ((rb>>2)&ONE8);
    u64 e2 = e1 | (bcast(E_FIRE) & mexp(dbe));
    u64 fe = eqb(e2,E_FIRE) & ((rb>>3)&ONE8) & eqb(HBNs[l+1][w], 0);
    EFs[l][w] = e2 & ~mexp(fe);
  }
  {
    const unsigned char* B1b = reinterpret_cast<const unsigned char*>(&B1s[0][0]);
    int x = tid;
    int xl1 = (x + 511) & 511, xr1 = (x + 1) & 511;
    #pragma unroll
    for (int r = 0; r < 4; ++r) {
      int gy = ty + r;
      int fu  = B1b[(r+3)*512 + x];
      int fd_ = B1b[(r+5)*512 + x];
      int flf = B1b[(r+4)*512 + xl1];
      int frt = B1b[(r+4)*512 + xr1];
      float vy = vin[(size_t)(b*2+0)*HW + (gy<<9) + x];
      vy = vy + 2.0f*(float)((fu>>4)&1);   vy = vy - 2.0f*(float)((fd_>>4)&1);
      vy = vy + 20.0f*(float)((fu>>5)&1);  vy = vy - 20.0f*(float)((fd_>>5)&1);
      float vx = vin[(size_t)(b*2+1)*HW + (gy<<9) + x];
      vx = vx + 2.0f*(float)((flf>>4)&1);  vx = vx - 2.0f*(float)((frt>>4)&1);
      vx = vx + 20.0f*(float)((flf>>5)&1); vx = vx - 20.0f*(float)((frt>>5)&1);
      vout[(size_t)(b*2+0)*HW + (gy<<9) + x] = vy;
      vout[(size_t)(b*2+1)*HW + (gy<<9) + x] = vx;
    }
  }
  __syncthreads();

  // ---- fluid: 8 waves own EF rows 0..7 (abs ty+w8-2); registers + edge shuffles
  {
    int w8 = tid >> 6, lane = tid & 63;
    const unsigned char* EFb = reinterpret_cast<const unsigned char*>(&EFs[0][0]);
    const unsigned char* RBb = reinterpret_cast<const unsigned char*>(&RBs[0][0]);
    uint2 ev = *reinterpret_cast<const uint2*>(EFb + w8*512 + (lane << 3));
    int E0 =  ev.x        & 255, E1 = (ev.x >> 8) & 255,
        E2 = (ev.x >> 16) & 255, E3 = (ev.x >> 24) & 255,
        E4 =  ev.y        & 255, E5 = (ev.y >> 8) & 255,
        E6 = (ev.y >> 16) & 255, E7 = (ev.y >> 24) & 255;
    uint2 qv = *reinterpret_cast<const uint2*>(RBb + (w8+4)*512 + (lane << 3));
    int rmb = ((qv.x>>4)&1) | (((qv.x>>12)&1)<<1) | (((qv.x>>20)&1)<<2) | (((qv.x>>28)&1)<<3)
            | (((qv.y>>4)&1)<<4) | (((qv.y>>12)&1)<<5) | (((qv.y>>20)&1)<<6) | (((qv.y>>28)&1)<<7);
    int nd0 = (qv.x>>5)&1,  nd1 = (qv.x>>13)&1, nd2 = (qv.x>>21)&1, nd3 = (qv.x>>29)&1,
        nd4 = (qv.y>>5)&1,  nd5 = (qv.y>>13)&1, nd6 = (qv.y>>21)&1, nd7 = (qv.y>>29)&1;
    int P0=PROPS(E0), P1=PROPS(E1), P2=PROPS(E2), P3=PROPS(E3),
        P4=PROPS(E4), P5=PROPS(E5), P6=PROPS(E6), P7=PROPS(E7);
    int M0=0,M1=0,M2=0,M3=0,M4=0,M5=0,M6=0,M7=0;

    int laneL = (lane + 63) & 63, laneR = (lane + 1) & 63;
    int ndpk = nd0 | (nd7 << 1);
    int ndl = (__shfl(ndpk, laneL, 64) >> 1) & 1;
    int ndr =  __shfl(ndpk, laneR, 64) & 1;

    #pragma unroll
    for (int ei = 0; ei < 5; ++ei) {
      const int el = (ei==0) ? E_EMPTY : (ei==1) ? E_WATER : (ei==2) ? E_GAS
                   : (ei==3) ? E_LAVA  : E_ACID;
      { // fall_left
        FDEF;
        int pl_ = __shfl(E7 | (f7 << 8) | (P7 << 9), laneL, 64);
        int pr_ = __shfl(E0 | (f0 << 8) | (P0 << 9), laneR, 64);
        int EBL = pl_ & 255, PBL = (pl_ >> 9) & 31;
        int EBR = pr_ & 255, FBR = (pr_ >> 8) & 1, PBR = (pr_ >> 9) & 31;
        int N0,N1,N2,N3,N4,N5,N6,N7, Q0,Q1,Q2,Q3,Q4,Q5,Q6,Q7;
        STEPL(N0,Q0,E0,P0,EBL,PBL,E1,P1,f0,f1, nd0,nd1,M0);
        STEPL(N1,Q1,E1,P1,E0, P0, E2,P2,f1,f2, nd1,nd2,M1);
        STEPL(N2,Q2,E2,P2,E1, P1, E3,P3,f2,f3, nd2,nd3,M2);
        STEPL(N3,Q3,E3,P3,E2, P2, E4,P4,f3,f4, nd3,nd4,M3);
        STEPL(N4,Q4,E4,P4,E3, P3, E5,P5,f4,f5, nd4,nd5,M4);
        STEPL(N5,Q5,E5,P5,E4, P4, E6,P6,f5,f6, nd5,nd6,M5);
        STEPL(N6,Q6,E6,P6,E5, P5, E7,P7,f6,f7, nd6,nd7,M6);
        STEPL(N7,Q7,E7,P7,E6, P6,EBR,PBR,f7,FBR,nd7,ndr,M7);
        E0=N0;E1=N1;E2=N2;E3=N3;E4=N4;E5=N5;E6=N6;E7=N7;
        P0=Q0;P1=Q1;P2=Q2;P3=Q3;P4=Q4;P5=Q5;P6=Q6;P7=Q7;
      }
      { // fall_right
        FDEF;
        int pl_ = __shfl(E7 | (f7 << 8) | (P7 << 9), laneL, 64);
        int pr_ = __shfl(E0 | (f0 << 8) | (P0 << 9), laneR, 64);
        int EBL = pl_ & 255, FBL = (pl_ >> 8) & 1, PBL = (pl_ >> 9) & 31;
        int EBR = pr_ & 255, PBR = (pr_ >> 9) & 31;
        int N0,N1,N2,N3,N4,N5,N6,N7, Q0,Q1,Q2,Q3,Q4,Q5,Q6,Q7;
        STEPR(N0,Q0,E0,P0,EBL,PBL,E1,P1,f0,FBL,nd0,ndl,M0);
        STEPR(N1,Q1,E1,P1,E0, P0, E2,P2,f1,f0, nd1,nd0,M1);
        STEPR(N2,Q2,E2,P2,E1, P1, E3,P3,f2,f1, nd2,nd1,M2);
        STEPR(N3,Q3,E3,P3,E2, P2, E4,P4,f3,f2, nd3,nd2,M3);
        STEPR(N4,Q4,E4,P4,E3, P3, E5,P5,f4,f3, nd4,nd3,M4);
        STEPR(N5,Q5,E5,P5,E4, P4, E6,P6,f5,f4, nd5,nd4,M5);
        STEPR(N6,Q6,E6,P6,E5, P5, E7,P7,f6,f5, nd6,nd5,M6);
        STEPR(N7,Q7,E7,P7,E6, P6,EBR,PBR,f7,f6, nd7,nd6,M7);
        E0=N0;E1=N1;E2=N2;E3=N3;E4=N4;E5=N5;E6=N6;E7=N7;
        P0=Q0;P1=Q1;P2=Q2;P3=Q3;P4=Q4;P5=Q5;P6=Q6;P7=Q7;
      }
    }
    unsigned int w0 = (unsigned)E0 | ((unsigned)E1<<8) | ((unsigned)E2<<16) | ((unsigned)E3<<24);
    unsigned int w1 = (unsigned)E4 | ((unsigned)E5<<8) | ((unsigned)E6<<16) | ((unsigned)E7<<24);
    *reinterpret_cast<uint2*>(reinterpret_cast<unsigned char*>(&ELs[0][0]) + w8*512 + (lane << 3)) =
        make_uint2(w0, w1);
    if (w8 >= 2 && w8 < 6) {
      unsigned int m0 = (M0&255) | ((M1&255)<<8) | ((M2&255)<<16) | ((unsigned)(M3&255)<<24);
      unsigned int m1 = (M4&255) | ((M5&255)<<8) | ((M6&255)<<16) | ((unsigned)(M7&255)<<24);
      *reinterpret_cast<uint2*>(reinterpret_cast<unsigned char*>(&nms[w8-2][0]) + (lane << 3)) =
          make_uint2(m0, m1);
    }
  }
  __syncthreads();

  // ---- cloner + expand to 18-ch output: 512 threads, quad (row r=tid>>7, x0=(tid&127)*4)
  {
    const unsigned char* ELb = reinterpret_cast<const unsigned char*>(&ELs[0][0]);
    int r = tid >> 7;               // 0..3
    int x0 = (tid & 127) << 2;
    const int DY[4] = {1, -1, 0, 0};
    const int DX[4] = {0, 0, -1, 1};
    int eo[4]; float mom[4], cao[4];
    #pragma unroll
    for (int k = 0; k < 4; ++k) {
      int xx = x0 + k;
      int ry = r + 2;               // EL row of this cell
      int ec = ELb[ry*512 + xx];
      float m = (float)nms[r][xx];
      int e = ec; float ca = 0.f;
      if (ec == E_CLONER) {
        int c = ELb[(ry+1)*512 + xx];
        if (c==0||c==13) c = ELb[(ry-1)*512 + xx];
        if (c==0||c==13) c = ELb[ry*512 + ((xx+511)&511)];
        if (c==0||c==13) c = ELb[ry*512 + ((xx+1)&511)];
        ca = (float)c;
      } else if (ec == E_EMPTY) {
        #pragma unroll
        for (int d = 0; d < 4; ++d) {
          int qy = r + 2 + DY[d], qx = (xx + DX[d]) & 511;
          if (ELb[qy*512 + qx] == E_CLONER) {
            int c = ELb[(qy+1)*512 + qx];
            if (c==0||c==13) c = ELb[(qy-1)*512 + qx];
            if (c==0||c==13) c = ELb[qy*512 + ((qx+511)&511)];
            if (c==0||c==13) c = ELb[qy*512 + ((qx+1)&511)];
            if (c != 0 && c != 13) { e = c; m = 0.f; break; }
          }
        }
      }
      eo[k] = e; mom[k] = m; cao[k] = ca;
    }
    float* ob = out + (size_t)b * CH * HW + ((ty + r) << 9) + x0;
    #pragma unroll
    for (int c = 0; c < 14; ++c) {
      float4 v = make_float4(eo[0]==c ? 1.f : 0.f, eo[1]==c ? 1.f : 0.f,
                             eo[2]==c ? 1.f : 0.f, eo[3]==c ? 1.f : 0.f);
      *reinterpret_cast<float4*>(ob + (size_t)c * HW) = v;
    }
    *reinterpret_cast<float4*>(ob + (size_t)14*HW) =
        make_float4(c_dens[eo[0]], c_dens[eo[1]], c_dens[eo[2]], c_dens[eo[3]]);
    *reinterpret_cast<float4*>(ob + (size_t)15*HW) =
        make_float4(c_grav[eo[0]], c_grav[eo[1]], c_grav[eo[2]], c_grav[eo[3]]);
    *reinterpret_cast<float4*>(ob + (size_t)16*HW) =
        make_float4(mom[0], mom[1], mom[2], mom[3]);
    *reinterpret_cast<float4*>(ob + (size_t)17*HW) =
        make_float4(cao[0], cao[1], cao[2], cao[3]);
  }
}

extern "C" void kernel_launch(void* const* d_in, const int* in_sizes, int n_in,
                              void* d_out, int out_size, void* d_ws, size_t ws_size,
                              hipStream_t stream) {
  const float* world = (const float*)d_in[0];
  const float* rm    = (const float*)d_in[1];
  const float* ri    = (const float*)d_in[2];
  const float* re    = (const float*)d_in[3];
  const float* vel   = (const float*)d_in[4];
  const float* dg    = (const float*)d_in[5];
  float* out = (float*)d_out;

  char* ws = (char*)d_ws;
  unsigned char* e0 = (unsigned char*)ws;
  unsigned char* rb = e0 + NPIX;

  hipLaunchKernelGGL(k_prep, dim3(NPIX/1024), dim3(256), 0, stream,
                     world, ri, re, rm, dg, e0, rb);
  hipLaunchKernelGGL(k_rest, dim3(4*128), dim3(512), 0, stream,
                     e0, rb, vel, out);
}